// Round 9
// baseline (37.225 us; speedup 1.0000x reference)
//
#include <hip/hip_runtime.h>
#include <math.h>

// Kaldi LinearResample 16000 -> 22050, LPW=6.
// P=441 phases, STRIDE=320, W=13 taps, tot = 441*3000 = 125 chunks of 24 m.
// R9 structure: block = (batch, 24-m chunk), 448 threads (7 waves).
//   1) stage contiguous 7700-float input window -> LDS (dense float4,
//      zero-padded OOB),
//   2) thread t<441 (g=t%147, third=t/147) computes GPW=3 outputs x 8 m
//      from LDS; 15 float4 weights in registers,
//   3) direct ob[t..t+2] stores (dwordx3; L2 write-back coalesces).
// R9 changes vs R8:
//   - dot20: 5 independent 4-FMA chains + add tree. The old "a+b+c+..." form
//     was a 19-deep serial FP add chain (~80 cyc latency per dot, no
//     reassociation without fast-math) -> VALUBusy stuck <20% in R2-R8.
//   - table kernel in f32 with EXACT integer dt (num = ii*22050 - p*16000,
//     window test |num|<=133636) + __sinf/__cosf: ~1e-5 weight error,
//     ~1e-4 output error vs 0.1025 threshold; kills the f64 sincos tail.
#define ORIG_F 16000
#define NEW_F  22050
#define P      441
#define STRIDE 320
#define GPW    3
#define NG     147         // 441/3
#define W20    20
#define MBLK   24          // m per block
#define MCH    125         // 3000/MBLK
#define BATCH  8
#define TILE_F 7700        // gab[146]+8+23*320+20 = 7700 exactly (30.8 KB)

#ifndef M_PI
#define M_PI 3.14159265358979323846
#endif

// fi[p] = ceil(p*320/441 - 6.060606..) = q - 6 + (r<=26 ? 0 : 1),
// where q = p*320/441, r = p*320 - q*441  (exact integer form).
__device__ __forceinline__ int kaldi_fi_int(int p) {
    int q = (p * 320) / 441;
    int r = p * 320 - q * 441;
    return q - 6 + (r <= 26 ? 0 : 1);
}

// One thread per (phase, slot j in [0,20)): w20[p][j] = weight applied to
// x[gab[p/3] + j] for phase p; slots outside the 13-tap support get |dt|>=ww
// and are naturally 0. gab[g] = fi[3g] & ~3.
__global__ void build_table20_f32(float* __restrict__ w20, int* __restrict__ gab) {
    int idx = blockIdx.x * blockDim.x + threadIdx.x;
    if (idx >= P * W20) return;
    int p = idx / W20;
    int j = idx - p * W20;
    int fi0 = kaldi_fi_int((p / GPW) * GPW);
    int ab = fi0 & ~3;
    if (j == 0 && (p % GPW) == 0) gab[p / GPW] = ab;
    int ii = ab + j;                                   // absolute input index
    // dt = ii/16000 - p/22050 = num / 352800000, num exact in int32 range
    int num = ii * 22050 - p * 16000;
    float wf = 0.f;
    if (num == 0) {
        wf = 0.99f;                                    // 2*cutoff/ORIG = 15840/16000
    } else if (num <= 133636 && num >= -133636) {      // |dt| < ww exactly
        float dt = (float)num * (1.0f / 352800000.0f);
        float hann = 0.5f * (1.0f + __cosf(2.0f * (float)M_PI * 1320.0f * dt));
        float s = __sinf(2.0f * (float)M_PI * 7920.0f * dt);
        wf = hann * s / ((float)M_PI * dt) * (1.0f / 16000.0f);
    }
    w20[idx] = wf;
}

// 5 independent 4-FMA chains + add tree: critical path ~24 cyc vs ~80 for
// the naive left-assoc sum (FP adds are not reassociable by the compiler).
__device__ __forceinline__ float dot20f(const float4& x0, const float4& x1,
                                        const float4& x2, const float4& x3,
                                        const float4& x4, const float4* w) {
    float p0 = x0.x * w[0].x;
    p0 = fmaf(x0.y, w[0].y, p0); p0 = fmaf(x0.z, w[0].z, p0); p0 = fmaf(x0.w, w[0].w, p0);
    float p1 = x1.x * w[1].x;
    p1 = fmaf(x1.y, w[1].y, p1); p1 = fmaf(x1.z, w[1].z, p1); p1 = fmaf(x1.w, w[1].w, p1);
    float p2 = x2.x * w[2].x;
    p2 = fmaf(x2.y, w[2].y, p2); p2 = fmaf(x2.z, w[2].z, p2); p2 = fmaf(x2.w, w[2].w, p2);
    float p3 = x3.x * w[3].x;
    p3 = fmaf(x3.y, w[3].y, p3); p3 = fmaf(x3.z, w[3].z, p3); p3 = fmaf(x3.w, w[3].w, p3);
    float p4 = x4.x * w[4].x;
    p4 = fmaf(x4.y, w[4].y, p4); p4 = fmaf(x4.z, w[4].z, p4); p4 = fmaf(x4.w, w[4].w, p4);
    return ((p0 + p1) + (p2 + p3)) + p4;
}

__global__ __launch_bounds__(448) void resample9_kernel(
    const float* __restrict__ x, const float* __restrict__ w20,
    const int* __restrict__ gab, float* __restrict__ out,
    int n, int tot)
{
    __shared__ float xt[TILE_F];

    const int b  = blockIdx.y;
    const int mc = blockIdx.x;
    const float* __restrict__ xb = x + (size_t)b * n;

    // Tile origin (global float index); S4 % 4 == 0 so float4 loads align.
    const int S4 = mc * (MBLK * STRIDE) - 8;

    // ---- stage input tile (dense, coalesced, zero-padded) ----
    for (int i4 = threadIdx.x; i4 < TILE_F / 4; i4 += 448) {
        const int gi = S4 + i4 * 4;
        float4 v;
        if (gi >= 0 && gi + 3 < n) {
            v = *(const float4*)(xb + gi);
        } else {
            float s[4];
            #pragma unroll
            for (int q = 0; q < 4; ++q) {
                int ii = gi + q;
                s[q] = (ii >= 0 && ii < n) ? xb[ii] : 0.f;
            }
            v = make_float4(s[0], s[1], s[2], s[3]);
        }
        *(float4*)(xt + i4 * 4) = v;
    }

    // ---- per-thread weights (overlaps staging loads) ----
    const int t = threadIdx.x;
    float4 w[15];
    int Lbase = 0;
    int tout = 0;
    const bool active = (t < P);
    if (active) {
        const int g     = t % NG;     // phase group
        const int third = t / NG;     // which 8-m slice
        const float4* wp = (const float4*)(w20 + g * (GPW * W20));
        #pragma unroll
        for (int i = 0; i < 15; ++i) w[i] = wp[i];
        Lbase = gab[g] + 8 + third * (8 * STRIDE);
        tout  = (mc * MBLK + third * 8) * P + GPW * g;
    }
    __syncthreads();

    // ---- compute: 3 outputs x 8 m-steps, direct dwordx3 stores ----
    if (active) {
        float* __restrict__ ob = out + (size_t)b * tot;
        #pragma unroll 1
        for (int k = 0; k < 8; ++k) {
            const float4* q4 = (const float4*)(xt + Lbase);
            float4 x0 = q4[0], x1 = q4[1], x2 = q4[2], x3 = q4[3], x4 = q4[4];
            float a0 = dot20f(x0, x1, x2, x3, x4, &w[0]);
            float a1 = dot20f(x0, x1, x2, x3, x4, &w[5]);
            float a2 = dot20f(x0, x1, x2, x3, x4, &w[10]);
            ob[tout]     = a0;        // merges to global_store_dwordx3
            ob[tout + 1] = a1;
            ob[tout + 2] = a2;
            Lbase += STRIDE; tout += P;
        }
    }
}

extern "C" void kernel_launch(void* const* d_in, const int* in_sizes, int n_in,
                              void* d_out, int out_size, void* d_ws, size_t ws_size,
                              hipStream_t stream) {
    const float* x = (const float*)d_in[0];
    float* out = (float*)d_out;

    const int n = in_sizes[0] / BATCH;     // 960000

    // Kaldi GetNumOutputSamples
    long long interval = (long long)n * P;
    long long last = interval / STRIDE;
    if (last * STRIDE == interval) last -= 1;
    const int tot = (int)(last + 1);       // 1,323,000 = 125 * 10584

    float* w20 = (float*)d_ws;
    int*   gab = (int*)((char*)d_ws + (size_t)P * W20 * sizeof(float));

    build_table20_f32<<<(P * W20 + 255) / 256, 256, 0, stream>>>(w20, gab);

    dim3 grid(MCH, BATCH);                 // 125 x 8 = 1000 blocks
    resample9_kernel<<<grid, 448, 0, stream>>>(x, w20, gab, out, n, tot);
}